// Round 4
// baseline (274.579 us; speedup 1.0000x reference)
//
#include <hip/hip_runtime.h>
#include <math.h>

typedef unsigned short u16;
typedef unsigned short u16x8 __attribute__((ext_vector_type(8)));
typedef __bf16 bf16v8 __attribute__((ext_vector_type(8)));
typedef float f32x4 __attribute__((ext_vector_type(4)));

static __device__ __forceinline__ float b2f(u16 u){ union{unsigned v; float f;} x; x.v=((unsigned)u)<<16; return x.f; }
static __device__ __forceinline__ u16 f2b(float f){ union{float f; unsigned v;} x; x.f=f; unsigned r=x.v+0x7fffu+((x.v>>16)&1u); return (u16)(r>>16); }
static __device__ __forceinline__ f32x4 mfma16(bf16v8 a, bf16v8 b, f32x4 c){
  return __builtin_amdgcn_mfma_f32_16x16x32_bf16(a,b,c,0,0,0);
}
#define GLDS16(g,l) __builtin_amdgcn_global_load_lds((const __attribute__((address_space(1))) unsigned*)(g), (__attribute__((address_space(3))) unsigned*)(l), 16, 0, 0)

// ---------------- convert f32 -> bf16 ----------------
__global__ __launch_bounds__(256) void convert_k(const float* __restrict__ src, u16* __restrict__ dst, int n8){
  int i = blockIdx.x*256 + threadIdx.x;
  if (i >= n8) return;
  const float* s = src + (size_t)i*8;
  f32x4 a = *(const f32x4*)s, b = *(const f32x4*)(s+4);
  u16x8 o;
  #pragma unroll
  for (int j=0;j<4;++j){ o[j] = f2b(a[j]); o[j+4] = f2b(b[j]); }
  *(u16x8*)(dst + (size_t)i*8) = o;
}

// ---------------- weight transpose: f32 in [R][C] -> bf16 out [C][R] ----------------
__global__ __launch_bounds__(256) void transpose_k(const float* __restrict__ in, u16* __restrict__ out, int R, int C){
  __shared__ u16 tile[64][66];
  int ct = C >> 6;
  int bx = blockIdx.x % ct, by = blockIdx.x / ct;
  int t = threadIdx.x;
  #pragma unroll
  for (int it=0; it<16; ++it){
    int idx = it*256 + t; int r = idx>>6, c = idx&63;
    tile[r][c] = f2b(in[(size_t)(by*64+r)*C + bx*64 + c]);
  }
  __syncthreads();
  #pragma unroll
  for (int it=0; it<16; ++it){
    int idx = it*256 + t; int c = idx>>6, r = idx&63;
    out[(size_t)(bx*64+c)*R + by*64 + r] = tile[r][c];
  }
}

// ---------------- rmsnorm: f32 in, f32 gamma, bf16 out ----------------
__global__ __launch_bounds__(256) void rmsn_k(const float* __restrict__ x, const float* __restrict__ g, u16* __restrict__ o){
  int w = threadIdx.x>>6, l = threadIdx.x&63;
  size_t row = (size_t)blockIdx.x*4 + w;
  const float* xr = x + row*512 + l*8;
  f32x4 a = *(const f32x4*)xr, b = *(const f32x4*)(xr+4);
  float f[8]; float ss = 0.f;
  #pragma unroll
  for (int j=0;j<4;++j){ f[j]=a[j]; f[j+4]=b[j]; }
  #pragma unroll
  for (int j=0;j<8;++j) ss += f[j]*f[j];
  #pragma unroll
  for (int m=1;m<64;m<<=1) ss += __shfl_xor(ss, m, 64);
  float inv = rsqrtf(ss*(1.0f/512.f) + 1e-6f);
  f32x4 ga = *(const f32x4*)(g + l*8), gb = *(const f32x4*)(g + l*8 + 4);
  u16x8 ov;
  #pragma unroll
  for (int j=0;j<4;++j){ ov[j] = f2b(f[j]*inv*(1.f + ga[j])); ov[j+4] = f2b(f[j+4]*inv*(1.f + gb[j])); }
  *(u16x8*)(o + row*512 + l*8) = ov;
}

// ---------------- GEMM: C[M,N] = A[M,K] @ BT[N,K]^T + bias, epilogues ----------------
// EPI 0: bias -> bf16 Cb
// EPI 1: bias + resid(f32) -> f32 Cf            (all_out)
// EPI 2: bias + exact gelu -> bf16 Cb
// EPI 3: bias + addf(f32) -> f32 Cf             (final output)
template<int BN, int EPI, bool CONCAT>
__global__ __launch_bounds__(256,2) void gemm_k(
  const u16* __restrict__ A, const u16* __restrict__ Avk, const u16* __restrict__ Avv,
  const u16* __restrict__ BT, const float* __restrict__ bias,
  u16* __restrict__ Cb, float* __restrict__ Cf,
  const float* __restrict__ resid, const float* __restrict__ addf,
  int M, int N, int K)
{
  constexpr int BM = 128, BK = 64;
  constexpr int NFR = BN/32;                     // per-wave N fragments (wave tile 64 x BN/2)
  __shared__ alignas(16) u16 sm[(BM+BN)*BK];
  u16* As = sm; u16* Bs = sm + BM*BK;
  const int t = threadIdx.x, w = t>>6, l = t&63, grp = l>>4, l16 = l&15;
  const int wr = w>>1, wc = w&1;
  const int m0 = blockIdx.y*BM, n0 = blockIdx.x*BN;

  f32x4 acc[4][NFR];
  #pragma unroll
  for (int m=0;m<4;++m)
    #pragma unroll
    for (int n=0;n<NFR;++n) acc[m][n] = f32x4{0.f,0.f,0.f,0.f};

  for (int k0 = 0; k0 < K; k0 += BK){
    // stage A tile [BM][BK] via global_load_lds, XOR-swizzled source (rule #21)
    #pragma unroll
    for (int it=0; it<4; ++it){
      int p16 = it*256 + t;
      int row = p16>>3; int offb = (p16&7)<<4;
      int swz = offb ^ ((row&7)<<4);
      const u16* src;
      if (CONCAT){
        int g = m0+row, bb = g>>10, ii = g&1023;
        const u16* base = (ii < 512) ? (Avk + (size_t)(bb*512+ii)*4096)
                                     : (Avv + (size_t)(bb*512+ii-512)*4096);
        src = base + k0 + (swz>>1);
      } else {
        src = A + (size_t)(m0+row)*K + k0 + (swz>>1);
      }
      GLDS16(src, As + (it*256 + w*64)*8);
    }
    // stage B tile [BN][BK]
    #pragma unroll
    for (int it=0; it<NFR; ++it){
      int p16 = it*256 + t;
      int row = p16>>3; int offb = (p16&7)<<4;
      int swz = offb ^ ((row&7)<<4);
      const u16* src = BT + (size_t)(n0+row)*K + k0 + (swz>>1);
      GLDS16(src, Bs + (it*256 + w*64)*8);
    }
    __syncthreads();

    bf16v8 af[4][2], bfr[NFR][2];
    #pragma unroll
    for (int kk=0;kk<2;++kk){
      #pragma unroll
      for (int m=0;m<4;++m){
        int row = wr*64 + m*16 + l16;
        int offb = (kk*64 + grp*16) ^ ((row&7)<<4);
        af[m][kk] = *(const bf16v8*)((const char*)As + row*128 + offb);
      }
      #pragma unroll
      for (int n=0;n<NFR;++n){
        int row = wc*(BN/2) + n*16 + l16;
        int offb = (kk*64 + grp*16) ^ ((row&7)<<4);
        bfr[n][kk] = *(const bf16v8*)((const char*)Bs + row*128 + offb);
      }
    }
    #pragma unroll
    for (int kk=0;kk<2;++kk)
      #pragma unroll
      for (int m=0;m<4;++m)
        #pragma unroll
        for (int n=0;n<NFR;++n)
          acc[m][n] = mfma16(af[m][kk], bfr[n][kk], acc[m][n]);
    __syncthreads();
  }

  // epilogue: C/D layout col=lane&15, row=(lane>>4)*4+reg
  #pragma unroll
  for (int m=0;m<4;++m){
    #pragma unroll
    for (int n=0;n<NFR;++n){
      #pragma unroll
      for (int r=0;r<4;++r){
        int row = m0 + wr*64 + m*16 + grp*4 + r;
        int col = n0 + wc*(BN/2) + n*16 + l16;
        size_t idx = (size_t)row*N + col;
        float v = acc[m][n][r] + bias[col];
        if (EPI == 0){
          Cb[idx] = f2b(v);
        } else if (EPI == 1){
          Cf[idx] = v + resid[idx];
        } else if (EPI == 2){
          v = 0.5f*v*(1.f + erff(v*0.70710678f));
          Cb[idx] = f2b(v);
        } else {
          Cf[idx] = v + addf[idx];
        }
      }
    }
  }
}

// ---------------- scatter q/k with rope; copy sk into KEYS ----------------
__global__ __launch_bounds__(256) void scatter_qk(const u16* __restrict__ qkv, const u16* __restrict__ skv,
                                                  u16* __restrict__ Qh, u16* __restrict__ KEYS){
  int bi = blockIdx.x;             // row = b*1024 + i
  int b = bi>>10, i = bi&1023;
  int t = threadIdx.x;
  int h = t>>5, dp = t&31;
  const u16* qrow = qkv + (size_t)bi*1536;
  float invf = __expf(-(float)dp * (9.2103403720f/32.f));  // 10000^(-dp/32)
  float fr = (float)i * invf;
  float sn, cs; sincosf(fr, &sn, &cs);
  int bh = b*8 + h;
  // q
  float x1 = b2f(qrow[h*64+dp]), x2 = b2f(qrow[h*64+dp+32]);
  u16* qd = Qh + ((size_t)bh*1024 + i)*64;
  qd[dp]    = f2b(x1*cs - x2*sn);
  qd[dp+32] = f2b(x2*cs + x1*sn);
  // k -> KEYS rows [512 + i]
  x1 = b2f(qrow[512+h*64+dp]); x2 = b2f(qrow[512+h*64+dp+32]);
  u16* kd = KEYS + ((size_t)bh*1536 + 512 + i)*64;
  kd[dp]    = f2b(x1*cs - x2*sn);
  kd[dp+32] = f2b(x2*cs + x1*sn);
  // sk copy (no rope) -> KEYS rows [0..511]
  if (i < 512){
    const u16* skrow = skv + ((size_t)b*1024 + i)*512;
    for (int e = t; e < 512; e += 256){
      int hh = e>>6, d = e&63;
      KEYS[((size_t)(b*8+hh)*1536 + i)*64 + d] = skrow[e];
    }
  }
}

// ---------------- build transposed values VT[bh][d][j] ----------------
__global__ __launch_bounds__(256) void build_vt(const u16* __restrict__ qkv, const u16* __restrict__ skv,
                                                u16* __restrict__ VT){
  __shared__ u16 tile[64][66];
  int blk = blockIdx.x;
  int bh = blk / 24, tt = blk % 24;
  int b = bh>>3, h = bh&7;
  int t = threadIdx.x;
  int jbase;
  if (tt < 16){            // v tile: i0 = tt*64 -> j = 512 + i
    int i0 = tt*64; jbase = 512 + i0;
    #pragma unroll
    for (int it=0; it<16; ++it){
      int idx = it*256+t; int r = idx>>6, c = idx&63;
      tile[r][c] = qkv[((size_t)b*1024 + i0 + r)*1536 + 1024 + h*64 + c];
    }
  } else {                 // sv tile: j0 = (tt-16)*64
    int j0 = (tt-16)*64; jbase = j0;
    #pragma unroll
    for (int it=0; it<16; ++it){
      int idx = it*256+t; int r = idx>>6, c = idx&63;
      tile[r][c] = skv[((size_t)b*1024 + 512 + j0 + r)*512 + h*64 + c];
    }
  }
  __syncthreads();
  #pragma unroll
  for (int it=0; it<16; ++it){
    int idx = it*256+t; int c = idx>>6, r = idx&63;
    VT[((size_t)bh*64 + c)*1536 + jbase + r] = tile[r][c];
  }
}

// ---------------- flash attention ----------------
// grid: 256 = 32 (b,h) * 8 q-tiles of 128; 4 waves, each owns 32 q-rows (independent)
__global__ __launch_bounds__(256,2) void attn_k(const u16* __restrict__ Qh, const u16* __restrict__ KEYS,
                                                const u16* __restrict__ VT, u16* __restrict__ AO){
  __shared__ alignas(16) u16 Pl[4][32*72];
  const int t = threadIdx.x, w = t>>6, l = t&63, grp = l>>4, l16 = l&15;
  const int bh = blockIdx.x >> 3, qt = blockIdx.x & 7;
  const int b = bh>>3, h = bh&7;
  const int i0 = qt*128 + w*32;
  const u16* Qb = Qh + (size_t)bh*1024*64;
  const u16* Kb = KEYS + (size_t)bh*1536*64;
  const u16* Vb = VT + (size_t)bh*64*1536;
  u16* Pw = &Pl[w][0];

  bf16v8 qf[2][2];
  #pragma unroll
  for (int m=0;m<2;++m)
    #pragma unroll
    for (int kk=0;kk<2;++kk)
      qf[m][kk] = *(const bf16v8*)(Qb + (size_t)(i0 + m*16 + l16)*64 + kk*32 + grp*8);

  f32x4 O[2][4]; float mrun[2][4], lrun[2][4];
  #pragma unroll
  for (int m=0;m<2;++m)
    #pragma unroll
    for (int n=0;n<4;++n) O[m][n] = f32x4{0.f,0.f,0.f,0.f};
  #pragma unroll
  for (int m=0;m<2;++m)
    #pragma unroll
    for (int r=0;r<4;++r){ mrun[m][r] = -1e30f; lrun[m][r] = 0.f; }

  int jmax = i0 + 544; if (jmax > 1536) jmax = 1536;
  for (int j0 = 0; j0 < jmax; j0 += 64){
    f32x4 S[2][4];
    #pragma unroll
    for (int m=0;m<2;++m)
      #pragma unroll
      for (int n=0;n<4;++n) S[m][n] = f32x4{0.f,0.f,0.f,0.f};
    #pragma unroll
    for (int kk=0;kk<2;++kk)
      #pragma unroll
      for (int n=0;n<4;++n){
        bf16v8 kf = *(const bf16v8*)(Kb + (size_t)(j0 + n*16 + l16)*64 + kk*32 + grp*8);
        #pragma unroll
        for (int m=0;m<2;++m) S[m][n] = mfma16(qf[m][kk], kf, S[m][n]);
      }
    const bool tail = (j0 + 63 > i0 + 512);
    #pragma unroll
    for (int m=0;m<2;++m){
      #pragma unroll
      for (int r=0;r<4;++r){
        int irow = i0 + m*16 + grp*4 + r;
        float sv[4]; float rm = -1e30f;
        #pragma unroll
        for (int n=0;n<4;++n){
          float s = S[m][n][r] * 0.125f;
          if (tail && (j0 + n*16 + l16 > irow + 512)) s = -1e30f;
          sv[n] = s; rm = fmaxf(rm, s);
        }
        #pragma unroll
        for (int msk=1; msk<16; msk<<=1) rm = fmaxf(rm, __shfl_xor(rm, msk, 64));
        float mold = mrun[m][r];
        float mnew = fmaxf(mold, rm);
        float alpha = __expf(mold - mnew);
        float rs = 0.f;
        #pragma unroll
        for (int n=0;n<4;++n){
          float p = __expf(sv[n] - mnew);
          rs += p;
          Pw[(m*16 + grp*4 + r)*72 + n*16 + l16] = f2b(p);
        }
        #pragma unroll
        for (int msk=1; msk<16; msk<<=1) rs += __shfl_xor(rs, msk, 64);
        lrun[m][r] = lrun[m][r]*alpha + rs;
        mrun[m][r] = mnew;
        #pragma unroll
        for (int n=0;n<4;++n) O[m][n][r] *= alpha;
      }
    }
    asm volatile("s_waitcnt lgkmcnt(0)" ::: "memory");   // P writes -> P reads (same wave)
    __builtin_amdgcn_sched_barrier(0);
    #pragma unroll
    for (int kk=0;kk<2;++kk){
      bf16v8 pa[2];
      #pragma unroll
      for (int m=0;m<2;++m)
        pa[m] = *(const bf16v8*)(Pw + (m*16 + l16)*72 + kk*32 + grp*8);
      #pragma unroll
      for (int n=0;n<4;++n){
        bf16v8 vf = *(const bf16v8*)(Vb + (size_t)(n*16 + l16)*1536 + j0 + kk*32 + grp*8);
        #pragma unroll
        for (int m=0;m<2;++m) O[m][n] = mfma16(pa[m], vf, O[m][n]);
      }
    }
  }
  // epilogue: AO[b, i, h*64 + d]
  #pragma unroll
  for (int m=0;m<2;++m)
    #pragma unroll
    for (int r=0;r<4;++r){
      int irow = i0 + m*16 + grp*4 + r;
      float inv = 1.0f / lrun[m][r];
      u16* dst = AO + ((size_t)b*1024 + irow)*512 + h*64;
      #pragma unroll
      for (int n=0;n<4;++n) dst[n*16 + l16] = f2b(O[m][n][r] * inv);
    }
}

// ---------------- launcher ----------------
extern "C" void kernel_launch(void* const* d_in, const int* in_sizes, int n_in,
                              void* d_out, int out_size, void* d_ws, size_t ws_size,
                              hipStream_t stream) {
  const float* planning = (const float*)d_in[0];
  const float* vk   = (const float*)d_in[1];
  const float* vv   = (const float*)d_in[2];
  const float* Wskv = (const float*)d_in[3];
  const float* bskv = (const float*)d_in[4];
  const float* Wqkv = (const float*)d_in[5];
  const float* bqkv = (const float*)d_in[6];
  const float* Wout = (const float*)d_in[7];
  const float* bout = (const float*)d_in[8];
  const float* Wff1 = (const float*)d_in[9];
  const float* bff1 = (const float*)d_in[10];
  const float* Wff2 = (const float*)d_in[11];
  const float* bff2 = (const float*)d_in[12];
  const float* g1   = (const float*)d_in[13];
  const float* g2   = (const float*)d_in[14];
  float* outp = (float*)d_out;

  char* w8 = (char*)d_ws;
  size_t off = 0;
  auto take = [&](size_t n)->char*{ char* p = w8 + off; off += (n + 255) & ~(size_t)255; return p; };
  u16* vkc     = (u16*)take((size_t)4*512*4096*2);
  u16* vvc     = (u16*)take((size_t)4*512*4096*2);
  u16* WTqkv   = (u16*)take((size_t)1536*512*2);
  u16* WTskv   = (u16*)take((size_t)512*4096*2);
  u16* WTout   = (u16*)take((size_t)512*512*2);
  u16* WTff1   = (u16*)take((size_t)512*512*2);
  u16* WTff2   = (u16*)take((size_t)512*512*2);
  u16* normed1 = (u16*)take((size_t)4096*512*2);
  u16* qkv     = (u16*)take((size_t)4096*1536*2);
  u16* skv     = (u16*)take((size_t)4096*512*2);
  u16* Qh      = (u16*)take((size_t)32*1024*64*2);
  u16* KEYS    = (u16*)take((size_t)32*1536*64*2);
  u16* VT      = (u16*)take((size_t)32*64*1536*2);
  u16* AO      = (u16*)take((size_t)4096*512*2);
  float* all_out = (float*)take((size_t)4096*512*4);
  u16* normed2 = (u16*)take((size_t)4096*512*2);
  u16* h1      = (u16*)take((size_t)4096*512*2);
  (void)in_sizes; (void)n_in; (void)out_size; (void)ws_size;

  convert_k<<<dim3(4096), 256, 0, stream>>>(vk, vkc, 1048576);
  convert_k<<<dim3(4096), 256, 0, stream>>>(vv, vvc, 1048576);

  transpose_k<<<dim3(192), 256, 0, stream>>>(Wqkv, WTqkv, 512, 1536);
  transpose_k<<<dim3(512), 256, 0, stream>>>(Wskv, WTskv, 4096, 512);
  transpose_k<<<dim3(64),  256, 0, stream>>>(Wout, WTout, 512, 512);
  transpose_k<<<dim3(64),  256, 0, stream>>>(Wff1, WTff1, 512, 512);
  transpose_k<<<dim3(64),  256, 0, stream>>>(Wff2, WTff2, 512, 512);
  rmsn_k<<<dim3(1024), 256, 0, stream>>>(planning, g1, normed1);

  gemm_k<128,0,false><<<dim3(12,32), 256, 0, stream>>>(normed1,nullptr,nullptr, WTqkv, bqkv, qkv, nullptr, nullptr, nullptr, 4096, 1536, 512);
  gemm_k<64,0,true ><<<dim3(8,32),  256, 0, stream>>>(nullptr, vkc, vvc,       WTskv, bskv, skv, nullptr, nullptr, nullptr, 4096, 512, 4096);

  scatter_qk<<<dim3(4096), 256, 0, stream>>>(qkv, skv, Qh, KEYS);
  build_vt<<<dim3(768), 256, 0, stream>>>(qkv, skv, VT);

  attn_k<<<dim3(256), 256, 0, stream>>>(Qh, KEYS, VT, AO);

  gemm_k<64,1,false><<<dim3(8,32), 256, 0, stream>>>(AO, nullptr,nullptr, WTout, bout, nullptr, all_out, planning, nullptr, 4096, 512, 512);
  rmsn_k<<<dim3(1024), 256, 0, stream>>>(all_out, g2, normed2);
  gemm_k<64,2,false><<<dim3(8,32), 256, 0, stream>>>(normed2, nullptr,nullptr, WTff1, bff1, h1, nullptr, nullptr, nullptr, 4096, 512, 512);
  gemm_k<64,3,false><<<dim3(8,32), 256, 0, stream>>>(h1, nullptr,nullptr, WTff2, bff2, nullptr, outp, nullptr, all_out, 4096, 512, 512);
}

// Round 5
// 256.656 us; speedup vs baseline: 1.0698x; 1.0698x over previous
//
#include <hip/hip_runtime.h>
#include <math.h>

typedef unsigned short u16;
typedef unsigned short u16x8 __attribute__((ext_vector_type(8)));
typedef __bf16 bf16v8 __attribute__((ext_vector_type(8)));
typedef float f32x4 __attribute__((ext_vector_type(4)));

static __device__ __forceinline__ float b2f(u16 u){ union{unsigned v; float f;} x; x.v=((unsigned)u)<<16; return x.f; }
static __device__ __forceinline__ u16 f2b(float f){ union{float f; unsigned v;} x; x.f=f; unsigned r=x.v+0x7fffu+((x.v>>16)&1u); return (u16)(r>>16); }
static __device__ __forceinline__ f32x4 mfma16(bf16v8 a, bf16v8 b, f32x4 c){
  return __builtin_amdgcn_mfma_f32_16x16x32_bf16(a,b,c,0,0,0);
}
#define GLDS16(g,l) __builtin_amdgcn_global_load_lds((const __attribute__((address_space(1))) unsigned*)(g), (__attribute__((address_space(3))) unsigned*)(l), 16, 0, 0)

// ---------------- convert f32 -> bf16 ----------------
__global__ __launch_bounds__(256) void convert_k(const float* __restrict__ src, u16* __restrict__ dst, int n8){
  int i = blockIdx.x*256 + threadIdx.x;
  if (i >= n8) return;
  const float* s = src + (size_t)i*8;
  f32x4 a = *(const f32x4*)s, b = *(const f32x4*)(s+4);
  u16x8 o;
  #pragma unroll
  for (int j=0;j<4;++j){ o[j] = f2b(a[j]); o[j+4] = f2b(b[j]); }
  *(u16x8*)(dst + (size_t)i*8) = o;
}

// ---------------- weight transpose: f32 in [R][C] -> bf16 out [C][R] ----------------
__global__ __launch_bounds__(256) void transpose_k(const float* __restrict__ in, u16* __restrict__ out, int R, int C){
  __shared__ u16 tile[64][66];
  int ct = C >> 6;
  int bx = blockIdx.x % ct, by = blockIdx.x / ct;
  int t = threadIdx.x;
  #pragma unroll
  for (int it=0; it<16; ++it){
    int idx = it*256 + t; int r = idx>>6, c = idx&63;
    tile[r][c] = f2b(in[(size_t)(by*64+r)*C + bx*64 + c]);
  }
  __syncthreads();
  #pragma unroll
  for (int it=0; it<16; ++it){
    int idx = it*256 + t; int c = idx>>6, r = idx&63;
    out[(size_t)(bx*64+c)*R + by*64 + r] = tile[r][c];
  }
}

// ---------------- rmsnorm: f32 in, f32 gamma, bf16 out ----------------
__global__ __launch_bounds__(256) void rmsn_k(const float* __restrict__ x, const float* __restrict__ g, u16* __restrict__ o){
  int w = threadIdx.x>>6, l = threadIdx.x&63;
  size_t row = (size_t)blockIdx.x*4 + w;
  const float* xr = x + row*512 + l*8;
  f32x4 a = *(const f32x4*)xr, b = *(const f32x4*)(xr+4);
  float f[8]; float ss = 0.f;
  #pragma unroll
  for (int j=0;j<4;++j){ f[j]=a[j]; f[j+4]=b[j]; }
  #pragma unroll
  for (int j=0;j<8;++j) ss += f[j]*f[j];
  #pragma unroll
  for (int m=1;m<64;m<<=1) ss += __shfl_xor(ss, m, 64);
  float inv = rsqrtf(ss*(1.0f/512.f) + 1e-6f);
  f32x4 ga = *(const f32x4*)(g + l*8), gb = *(const f32x4*)(g + l*8 + 4);
  u16x8 ov;
  #pragma unroll
  for (int j=0;j<4;++j){ ov[j] = f2b(f[j]*inv*(1.f + ga[j])); ov[j+4] = f2b(f[j+4]*inv*(1.f + gb[j])); }
  *(u16x8*)(o + row*512 + l*8) = ov;
}

// ---------------- GEMM: C[M,N] = A[M,K] @ BT[N,K]^T + bias, epilogues ----------------
// EPI 0: bias -> bf16 Cb
// EPI 1: bias + resid(f32) -> f32 Cf            (all_out)
// EPI 2: bias + exact gelu -> bf16 Cb
// EPI 3: bias + addf(f32) -> f32 Cf             (final output)
template<int BN, int EPI, bool CONCAT>
__global__ __launch_bounds__(256,2) void gemm_k(
  const u16* __restrict__ A, const u16* __restrict__ Avk, const u16* __restrict__ Avv,
  const u16* __restrict__ BT, const float* __restrict__ bias,
  u16* __restrict__ Cb, float* __restrict__ Cf,
  const float* __restrict__ resid, const float* __restrict__ addf,
  int M, int N, int K)
{
  constexpr int BM = 128, BK = 64;
  constexpr int NFR = BN/32;                     // per-wave N fragments (wave tile 64 x BN/2)
  __shared__ alignas(16) u16 sm[(BM+BN)*BK];
  u16* As = sm; u16* Bs = sm + BM*BK;
  const int t = threadIdx.x, w = t>>6, l = t&63, grp = l>>4, l16 = l&15;
  const int wr = w>>1, wc = w&1;
  const int m0 = blockIdx.y*BM, n0 = blockIdx.x*BN;

  f32x4 acc[4][NFR];
  #pragma unroll
  for (int m=0;m<4;++m)
    #pragma unroll
    for (int n=0;n<NFR;++n) acc[m][n] = f32x4{0.f,0.f,0.f,0.f};

  for (int k0 = 0; k0 < K; k0 += BK){
    // stage A tile [BM][BK] via global_load_lds, XOR-swizzled source (rule #21)
    #pragma unroll
    for (int it=0; it<4; ++it){
      int p16 = it*256 + t;
      int row = p16>>3; int offb = (p16&7)<<4;
      int swz = offb ^ ((row&7)<<4);
      const u16* src;
      if (CONCAT){
        int g = m0+row, bb = g>>10, ii = g&1023;
        const u16* base = (ii < 512) ? (Avk + (size_t)(bb*512+ii)*4096)
                                     : (Avv + (size_t)(bb*512+ii-512)*4096);
        src = base + k0 + (swz>>1);
      } else {
        src = A + (size_t)(m0+row)*K + k0 + (swz>>1);
      }
      GLDS16(src, As + (it*256 + w*64)*8);
    }
    // stage B tile [BN][BK]
    #pragma unroll
    for (int it=0; it<NFR; ++it){
      int p16 = it*256 + t;
      int row = p16>>3; int offb = (p16&7)<<4;
      int swz = offb ^ ((row&7)<<4);
      const u16* src = BT + (size_t)(n0+row)*K + k0 + (swz>>1);
      GLDS16(src, Bs + (it*256 + w*64)*8);
    }
    __syncthreads();

    bf16v8 af[4][2], bfr[NFR][2];
    #pragma unroll
    for (int kk=0;kk<2;++kk){
      #pragma unroll
      for (int m=0;m<4;++m){
        int row = wr*64 + m*16 + l16;
        int offb = (kk*64 + grp*16) ^ ((row&7)<<4);
        af[m][kk] = *(const bf16v8*)((const char*)As + row*128 + offb);
      }
      #pragma unroll
      for (int n=0;n<NFR;++n){
        int row = wc*(BN/2) + n*16 + l16;
        int offb = (kk*64 + grp*16) ^ ((row&7)<<4);
        bfr[n][kk] = *(const bf16v8*)((const char*)Bs + row*128 + offb);
      }
    }
    #pragma unroll
    for (int kk=0;kk<2;++kk)
      #pragma unroll
      for (int m=0;m<4;++m)
        #pragma unroll
        for (int n=0;n<NFR;++n)
          acc[m][n] = mfma16(af[m][kk], bfr[n][kk], acc[m][n]);
    __syncthreads();
  }

  // epilogue: C/D layout col=lane&15, row=(lane>>4)*4+reg
  #pragma unroll
  for (int m=0;m<4;++m){
    #pragma unroll
    for (int n=0;n<NFR;++n){
      #pragma unroll
      for (int r=0;r<4;++r){
        int row = m0 + wr*64 + m*16 + grp*4 + r;
        int col = n0 + wc*(BN/2) + n*16 + l16;
        size_t idx = (size_t)row*N + col;
        float v = acc[m][n][r] + bias[col];
        if (EPI == 0){
          Cb[idx] = f2b(v);
        } else if (EPI == 1){
          Cf[idx] = v + resid[idx];
        } else if (EPI == 2){
          v = 0.5f*v*(1.f + erff(v*0.70710678f));
          Cb[idx] = f2b(v);
        } else {
          Cf[idx] = v + addf[idx];
        }
      }
    }
  }
}

// ---------------- scatter q/k with rope; copy sk into KEYS ----------------
__global__ __launch_bounds__(256) void scatter_qk(const u16* __restrict__ qkv, const u16* __restrict__ skv,
                                                  u16* __restrict__ Qh, u16* __restrict__ KEYS){
  int bi = blockIdx.x;             // row = b*1024 + i
  int b = bi>>10, i = bi&1023;
  int t = threadIdx.x;
  int h = t>>5, dp = t&31;
  const u16* qrow = qkv + (size_t)bi*1536;
  float invf = __expf(-(float)dp * (9.2103403720f/32.f));  // 10000^(-dp/32)
  float fr = (float)i * invf;
  float sn, cs; sincosf(fr, &sn, &cs);
  int bh = b*8 + h;
  // q
  float x1 = b2f(qrow[h*64+dp]), x2 = b2f(qrow[h*64+dp+32]);
  u16* qd = Qh + ((size_t)bh*1024 + i)*64;
  qd[dp]    = f2b(x1*cs - x2*sn);
  qd[dp+32] = f2b(x2*cs + x1*sn);
  // k -> KEYS rows [512 + i]
  x1 = b2f(qrow[512+h*64+dp]); x2 = b2f(qrow[512+h*64+dp+32]);
  u16* kd = KEYS + ((size_t)bh*1536 + 512 + i)*64;
  kd[dp]    = f2b(x1*cs - x2*sn);
  kd[dp+32] = f2b(x2*cs + x1*sn);
  // sk copy (no rope) -> KEYS rows [0..511]
  if (i < 512){
    const u16* skrow = skv + ((size_t)b*1024 + i)*512;
    for (int e = t; e < 512; e += 256){
      int hh = e>>6, d = e&63;
      KEYS[((size_t)(b*8+hh)*1536 + i)*64 + d] = skrow[e];
    }
  }
}

// ---------------- build transposed values VT[bh][d][j] ----------------
__global__ __launch_bounds__(256) void build_vt(const u16* __restrict__ qkv, const u16* __restrict__ skv,
                                                u16* __restrict__ VT){
  __shared__ u16 tile[64][66];
  int blk = blockIdx.x;
  int bh = blk / 24, tt = blk % 24;
  int b = bh>>3, h = bh&7;
  int t = threadIdx.x;
  int jbase;
  if (tt < 16){            // v tile: i0 = tt*64 -> j = 512 + i
    int i0 = tt*64; jbase = 512 + i0;
    #pragma unroll
    for (int it=0; it<16; ++it){
      int idx = it*256+t; int r = idx>>6, c = idx&63;
      tile[r][c] = qkv[((size_t)b*1024 + i0 + r)*1536 + 1024 + h*64 + c];
    }
  } else {                 // sv tile: j0 = (tt-16)*64
    int j0 = (tt-16)*64; jbase = j0;
    #pragma unroll
    for (int it=0; it<16; ++it){
      int idx = it*256+t; int r = idx>>6, c = idx&63;
      tile[r][c] = skv[((size_t)b*1024 + 512 + j0 + r)*512 + h*64 + c];
    }
  }
  __syncthreads();
  #pragma unroll
  for (int it=0; it<16; ++it){
    int idx = it*256+t; int c = idx>>6, r = idx&63;
    VT[((size_t)bh*64 + c)*1536 + jbase + r] = tile[r][c];
  }
}

// ---------------- flash attention, causal KV-split ----------------
// grid: 1024 = bh(32) * qgroup(16, 64 rows each) * split(2); 4 waves, each 16 q-rows.
// Split s covers keys [s*768, (s+1)*768) clipped by causal bound. Partials unnormalized.
__global__ __launch_bounds__(256,2) void attn_k(const u16* __restrict__ Qh, const u16* __restrict__ KEYS,
                                                const u16* __restrict__ VT,
                                                float* __restrict__ Op, float2* __restrict__ Ml2){
  __shared__ alignas(16) u16 Pl[4][16*72];
  const int t = threadIdx.x, w = t>>6, l = t&63, grp = l>>4, l16 = l&15;
  const int blk = blockIdx.x;
  const int s = blk & 1, qg = (blk>>1) & 15, bh = blk>>5;
  const int i0 = qg*64 + w*16;
  const int klo = s*768;
  int khi = i0 + 528; { int cap = (s+1)*768; if (khi > cap) khi = cap; }
  const size_t prow = ((size_t)s*32 + bh)*1024;   // partial row base for this split+head

  if (khi <= klo){                                 // wave fully masked: record empty partial
    if (l < 16) Ml2[prow + i0 + l] = make_float2(-1e30f, 0.f);
    return;
  }

  const u16* Qb = Qh + (size_t)bh*1024*64;
  const u16* Kb = KEYS + (size_t)bh*1536*64;
  const u16* Vb = VT + (size_t)bh*64*1536;
  u16* Pw = &Pl[w][0];

  bf16v8 qf[2];
  #pragma unroll
  for (int kk=0;kk<2;++kk)
    qf[kk] = *(const bf16v8*)(Qb + (size_t)(i0 + l16)*64 + kk*32 + grp*8);

  f32x4 O[4]; float mrun[4], lrun[4];
  #pragma unroll
  for (int n=0;n<4;++n) O[n] = f32x4{0.f,0.f,0.f,0.f};
  #pragma unroll
  for (int r=0;r<4;++r){ mrun[r] = -1e30f; lrun[r] = 0.f; }

  for (int j0 = klo; j0 < khi; j0 += 64){
    f32x4 S[4];
    #pragma unroll
    for (int n=0;n<4;++n) S[n] = f32x4{0.f,0.f,0.f,0.f};
    #pragma unroll
    for (int kk=0;kk<2;++kk)
      #pragma unroll
      for (int n=0;n<4;++n){
        bf16v8 kf = *(const bf16v8*)(Kb + (size_t)(j0 + n*16 + l16)*64 + kk*32 + grp*8);
        S[n] = mfma16(qf[kk], kf, S[n]);
      }
    const bool tail = (j0 + 63 > i0 + 512);
    #pragma unroll
    for (int r=0;r<4;++r){
      int irow = i0 + grp*4 + r;
      float sv[4]; float rm = -1e30f;
      #pragma unroll
      for (int n=0;n<4;++n){
        float sc = S[n][r] * 0.125f;
        if (tail && (j0 + n*16 + l16 > irow + 512)) sc = -1e30f;
        sv[n] = sc; rm = fmaxf(rm, sc);
      }
      #pragma unroll
      for (int msk=1; msk<16; msk<<=1) rm = fmaxf(rm, __shfl_xor(rm, msk, 64));
      float mold = mrun[r];
      float mnew = fmaxf(mold, rm);
      float alpha = __expf(mold - mnew);
      float rs = 0.f;
      #pragma unroll
      for (int n=0;n<4;++n){
        float p = __expf(sv[n] - mnew);
        rs += p;
        Pw[(grp*4 + r)*72 + n*16 + l16] = f2b(p);
      }
      #pragma unroll
      for (int msk=1; msk<16; msk<<=1) rs += __shfl_xor(rs, msk, 64);
      lrun[r] = lrun[r]*alpha + rs;
      mrun[r] = mnew;
      #pragma unroll
      for (int n=0;n<4;++n) O[n][r] *= alpha;
    }
    asm volatile("s_waitcnt lgkmcnt(0)" ::: "memory");   // P writes -> P reads (same wave)
    __builtin_amdgcn_sched_barrier(0);
    #pragma unroll
    for (int kk=0;kk<2;++kk){
      bf16v8 pa = *(const bf16v8*)(Pw + l16*72 + kk*32 + grp*8);
      #pragma unroll
      for (int n=0;n<4;++n){
        bf16v8 vf = *(const bf16v8*)(Vb + (size_t)(n*16 + l16)*1536 + j0 + kk*32 + grp*8);
        O[n] = mfma16(pa, vf, O[n]);
      }
    }
  }
  // write unnormalized partials
  #pragma unroll
  for (int r=0;r<4;++r){
    int irow = i0 + grp*4 + r;
    if (l16 == 0) Ml2[prow + irow] = make_float2(mrun[r], lrun[r]);
    float* dst = Op + (prow + irow)*64;
    #pragma unroll
    for (int n=0;n<4;++n) dst[n*16 + l16] = O[n][r];
  }
}

// ---------------- combine KV-split partials -> AO bf16 ----------------
__global__ __launch_bounds__(256) void attn_combine(const float* __restrict__ Op, const float2* __restrict__ Ml2,
                                                    u16* __restrict__ AO){
  int bi = blockIdx.x;                 // b*1024 + i
  int b = bi>>10, i = bi&1023;
  int t = threadIdx.x; int h = t>>6, d = t&63;
  int bh = b*8 + h;
  size_t r0 = (size_t)bh*1024 + i;
  size_t r1 = ((size_t)32 + bh)*1024 + i;
  float2 ml0 = Ml2[r0], ml1 = Ml2[r1];
  float M = fmaxf(ml0.x, ml1.x);
  float a0 = (ml0.y > 0.f) ? __expf(ml0.x - M) : 0.f;
  float a1 = (ml1.y > 0.f) ? __expf(ml1.x - M) : 0.f;
  float denom = a0*ml0.y + a1*ml1.y;
  float o0 = (a0 > 0.f) ? Op[r0*64 + d] : 0.f;
  float o1 = (a1 > 0.f) ? Op[r1*64 + d] : 0.f;
  float o = (a0*o0 + a1*o1) / denom;
  AO[((size_t)b*1024 + i)*512 + h*64 + d] = f2b(o);
}

// ---------------- launcher ----------------
extern "C" void kernel_launch(void* const* d_in, const int* in_sizes, int n_in,
                              void* d_out, int out_size, void* d_ws, size_t ws_size,
                              hipStream_t stream) {
  const float* planning = (const float*)d_in[0];
  const float* vk   = (const float*)d_in[1];
  const float* vv   = (const float*)d_in[2];
  const float* Wskv = (const float*)d_in[3];
  const float* bskv = (const float*)d_in[4];
  const float* Wqkv = (const float*)d_in[5];
  const float* bqkv = (const float*)d_in[6];
  const float* Wout = (const float*)d_in[7];
  const float* bout = (const float*)d_in[8];
  const float* Wff1 = (const float*)d_in[9];
  const float* bff1 = (const float*)d_in[10];
  const float* Wff2 = (const float*)d_in[11];
  const float* bff2 = (const float*)d_in[12];
  const float* g1   = (const float*)d_in[13];
  const float* g2   = (const float*)d_in[14];
  float* outp = (float*)d_out;

  char* w8 = (char*)d_ws;
  size_t off = 0;
  auto take = [&](size_t n)->char*{ char* p = w8 + off; off += (n + 255) & ~(size_t)255; return p; };
  u16* vkc     = (u16*)take((size_t)4*512*4096*2);
  u16* vvc     = (u16*)take((size_t)4*512*4096*2);
  u16* WTqkv   = (u16*)take((size_t)1536*512*2);
  u16* WTskv   = (u16*)take((size_t)512*4096*2);
  u16* WTout   = (u16*)take((size_t)512*512*2);
  u16* WTff1   = (u16*)take((size_t)512*512*2);
  u16* WTff2   = (u16*)take((size_t)512*512*2);
  u16* normed1 = (u16*)take((size_t)4096*512*2);
  u16* qkv     = (u16*)take((size_t)4096*1536*2);
  u16* skv     = (u16*)take((size_t)4096*512*2);
  u16* Qh      = (u16*)take((size_t)32*1024*64*2);
  u16* KEYS    = (u16*)take((size_t)32*1536*64*2);
  u16* VT      = (u16*)take((size_t)32*64*1536*2);
  u16* AO      = (u16*)take((size_t)4096*512*2);
  float* all_out = (float*)take((size_t)4096*512*4);
  u16* normed2 = (u16*)take((size_t)4096*512*2);
  u16* h1      = (u16*)take((size_t)4096*512*2);
  float* Op    = (float*)take((size_t)2*32*1024*64*4);
  float2* Ml2  = (float2*)take((size_t)2*32*1024*8);
  (void)in_sizes; (void)n_in; (void)out_size; (void)ws_size;

  convert_k<<<dim3(4096), 256, 0, stream>>>(vk, vkc, 1048576);
  convert_k<<<dim3(4096), 256, 0, stream>>>(vv, vvc, 1048576);

  transpose_k<<<dim3(192), 256, 0, stream>>>(Wqkv, WTqkv, 512, 1536);
  transpose_k<<<dim3(512), 256, 0, stream>>>(Wskv, WTskv, 4096, 512);
  transpose_k<<<dim3(64),  256, 0, stream>>>(Wout, WTout, 512, 512);
  transpose_k<<<dim3(64),  256, 0, stream>>>(Wff1, WTff1, 512, 512);
  transpose_k<<<dim3(64),  256, 0, stream>>>(Wff2, WTff2, 512, 512);
  rmsn_k<<<dim3(1024), 256, 0, stream>>>(planning, g1, normed1);

  gemm_k<128,0,false><<<dim3(12,32), 256, 0, stream>>>(normed1,nullptr,nullptr, WTqkv, bqkv, qkv, nullptr, nullptr, nullptr, 4096, 1536, 512);
  gemm_k<64,0,true ><<<dim3(8,32),  256, 0, stream>>>(nullptr, vkc, vvc,       WTskv, bskv, skv, nullptr, nullptr, nullptr, 4096, 512, 4096);

  scatter_qk<<<dim3(4096), 256, 0, stream>>>(qkv, skv, Qh, KEYS);
  build_vt<<<dim3(768), 256, 0, stream>>>(qkv, skv, VT);

  attn_k<<<dim3(1024), 256, 0, stream>>>(Qh, KEYS, VT, Op, Ml2);
  attn_combine<<<dim3(4096), 256, 0, stream>>>(Op, Ml2, AO);

  gemm_k<64,1,false><<<dim3(8,32), 256, 0, stream>>>(AO, nullptr,nullptr, WTout, bout, nullptr, all_out, planning, nullptr, 4096, 512, 512);
  rmsn_k<<<dim3(1024), 256, 0, stream>>>(all_out, g2, normed2);
  gemm_k<64,2,false><<<dim3(8,32), 256, 0, stream>>>(normed2, nullptr,nullptr, WTff1, bff1, h1, nullptr, nullptr, nullptr, 4096, 512, 512);
  gemm_k<64,3,false><<<dim3(8,32), 256, 0, stream>>>(h1, nullptr,nullptr, WTff2, bff2, nullptr, outp, nullptr, all_out, 4096, 512, 512);
}